// Round 23
// baseline (404.335 us; speedup 1.0000x reference)
//
#include <hip/hip_runtime.h>
#include <hip/hip_bf16.h>
#include <math.h>

#define B 8
#define T_MEL 400
#define N_MEL 80
#define L_TXT 128
#define D_TXT 512
#define E 256
#define HID 256
#define EMB 128
#define N_SPK 100
#define HH 128

// ---- workspace layout (float element offsets) ----
#define OFF_W      0
#define OFF_C      256
#define OFF_WXT    272
#define OFF_WQT    (OFF_WXT + N_MEL*E)        // 20752
#define OFF_WIHT   (OFF_WQT + D_TXT*E)        // 151824 ; uint[4][128][512] f16-pairs (view-cast)
#define OFF_BSUM   (OFF_WIHT + 2*2*256*512)   // 676112
#define OFF_X1     (OFF_BSUM + 2048)          // 678160
#define OFF_Q1     (OFF_X1 + B*T_MEL*E)       // 1497360
#define OFF_G      OFF_X1                      // gates overlay x1 (dead by then)
#define OFF_H0     (OFF_Q1 + B*L_TXT*E)       // 1759504
#define OFF_O1     (OFF_H0 + B*L_TXT*E)       // 2021648
#define OFF_HS0    OFF_H0                      // hseq[2][128][8][128] overlays H0
#define OFF_POOL   OFF_O1                      // pooled[2][8][128] floats (written by scan L1)
#define OFF_WG     (OFF_O1 + 4096)            // uint[4][8][4096] Whh f16-pairs, v20 lane-mapped

typedef _Float16 half2v __attribute__((ext_vector_type(2)));

__device__ __forceinline__ float fast_sigmoid(float x){ return 1.f/(1.f+__expf(-x)); }
__device__ __forceinline__ float fast_tanh(float x){ float e=__expf(2.f*x); return 1.f - 2.f/(e+1.f); }

__device__ __forceinline__ float fdot2(uint a, uint b, float c){
  half2v ha = __builtin_bit_cast(half2v, a);
  half2v hb = __builtin_bit_cast(half2v, b);
#if __has_builtin(__builtin_amdgcn_fdot2)
  return __builtin_amdgcn_fdot2(ha, hb, c, false);
#else
  float r;
  asm("v_dot2_f32_f16 %0, %1, %2, %3" : "=v"(r) : "v"(a), "v"(b), "v"(c));
  return r;
#endif
}
__device__ __forceinline__ uint packh2(float a, float b){
  union { _Float16 h[2]; uint u; } x;
  x.h[0] = (_Float16)a; x.h[1] = (_Float16)b; return x.u;
}

// ---- prep v4: tiled transposes + v20 weight pack ----
// blocks: 0 w/c | 1..4 WXT | 5..36 WQT | 37..68 WIHT | 69 BSUM | 70..101 WG(v20)
__global__ __launch_bounds__(256) void k_prep(const float* __restrict__ Wout, const float* __restrict__ bout,
                       const float* __restrict__ v,    const float* __restrict__ Wx,
                       const float* __restrict__ Wq,   const float* __restrict__ wih,
                       const float* __restrict__ bih,  const float* __restrict__ bhh,
                       const float* __restrict__ whh,  float* __restrict__ ws){
  __shared__ __align__(16) float tile[64][81];
  __shared__ __align__(16) uint  utile[64][129];
  int blk = blockIdx.x, tid = threadIdx.x;
  if (blk == 0){
    float acc = 0.f;
    for (int j=0;j<E;j++) acc += Wout[j*E + tid] * v[j];
    ws[OFF_W + tid] = acc;
    if (tid==0){ float c=0.f; for(int j=0;j<E;j++) c += bout[j]*v[j]; ws[OFF_C]=c; }
  } else if (blk <= 4){
    int e0 = (blk-1)*64;
    for (int idx = tid; idx < 64*20; idx += 256){
      int e = idx/20, c4 = idx%20;
      float4 vv = *(const float4*)&Wx[(size_t)(e0+e)*N_MEL + 4*c4];
      tile[e][4*c4]=vv.x; tile[e][4*c4+1]=vv.y; tile[e][4*c4+2]=vv.z; tile[e][4*c4+3]=vv.w;
    }
    __syncthreads();
    for (int idx = tid; idx < N_MEL*64; idx += 256){
      int m = idx>>6, e = idx&63;
      ws[OFF_WXT + m*E + e0 + e] = tile[e][m];
    }
  } else if (blk <= 36){
    int t = blk-5; int e0 = (t&3)*64, k0 = (t>>2)*64;
    for (int idx = tid; idx < 64*16; idx += 256){
      int e = idx>>4, c = idx&15;
      float4 vv = *(const float4*)&Wq[(size_t)(e0+e)*D_TXT + k0 + 4*c];
      tile[e][4*c]=vv.x; tile[e][4*c+1]=vv.y; tile[e][4*c+2]=vv.z; tile[e][4*c+3]=vv.w;
    }
    __syncthreads();
    for (int idx = tid; idx < 64*64; idx += 256){
      int k = idx>>6, e = idx&63;
      ws[OFF_WQT + (k0+k)*E + e0 + e] = tile[e][k];
    }
  } else if (blk <= 68){
    int t = blk-37; int ld = t>>3, g0 = (t&7)*64;
    for (int idx = tid; idx < 64*64; idx += 256){
      int g = idx>>6, c = idx&63;
      float4 vv = *(const float4*)&wih[((size_t)(ld*512+g0+g))*256 + 4*c];
      utile[g][2*c]   = packh2(vv.x, vv.y);
      utile[g][2*c+1] = packh2(vv.z, vv.w);
    }
    __syncthreads();
    uint* wout = (uint*)(ws + OFF_WIHT) + (size_t)ld*128*512;
    for (int idx = tid; idx < 128*64; idx += 256){
      int k2 = idx>>6, g = idx&63;
      wout[(size_t)k2*512 + g0 + g] = utile[g][k2];
    }
  } else if (blk == 69){
    for (int i = tid; i < 2048; i += 256)
      ws[OFF_BSUM + i] = bih[i] + bhh[i];
  } else {
    // v20 pack: wg[ld][w][ j*256 + l*4 + k ] ; thread (u=w*16+(l>>2), pr=(l>>1)&1, hf=l&1)
    // slot j: rsel=j>>3 (0: row pr*128+u ; 1: row 256+pr*128+u), jj=j&7 ; col=64hf+8jj+2k
    int bp = blk - 70;              // 0..31
    int ld = bp >> 3, w = bp & 7;
    uint* wg = (uint*)(ws + OFF_WG) + ((size_t)ld*8 + w)*4096;
    for (int ii = 0; ii < 16; ii++){
      int i = ii*256 + tid;         // 0..4095
      int j  = i >> 8;
      int l  = (i >> 2) & 63;
      int k  = i & 3;
      int rsel = j >> 3, jj = j & 7;
      int u  = w*16 + (l >> 2);
      int pr = (l >> 1) & 1;
      int hf = l & 1;
      int row = rsel ? (256 + pr*128 + u) : (pr*128 + u);
      const float* src = whh + ((size_t)(ld*512 + row))*HH + 64*hf + jj*8 + 2*k;
      wg[i] = packh2(src[0], src[1]);
    }
  }
}

// ---- x1 (blk<800) | q1 (blk 800..1055) ; reads WXT/WQT written by k_prep ----
__global__ __launch_bounds__(256) void k_xq(const float* __restrict__ x,    const float* __restrict__ bx,
                                            const float* __restrict__ text, const float* __restrict__ bq,
                                            float* __restrict__ ws){
  __shared__ float sbuf[2048];
  int blk = blockIdx.x, tid = threadIdx.x;
  if (blk < 800){
    int b = blk/100; int t0 = (blk%100)*4;
    float (*sx)[4] = (float(*)[4])sbuf;
    for (int i = tid; i < N_MEL*4; i += 256){
      int m = i>>2, ii = i&3;
      sx[m][ii] = x[(b*N_MEL+m)*T_MEL + t0 + ii];
    }
    __syncthreads();
    float bxe = bx[tid];
    float a0=bxe,a1=bxe,a2=bxe,a3=bxe;
    const float* wxt = ws + OFF_WXT;
    #pragma unroll 4
    for (int m=0;m<N_MEL;m++){
      float w = wxt[m*E + tid];
      a0 += sx[m][0]*w; a1 += sx[m][1]*w; a2 += sx[m][2]*w; a3 += sx[m][3]*w;
    }
    float* x1 = ws + OFF_X1 + (b*T_MEL + t0)*E + tid;
    x1[0]=a0; x1[E]=a1; x1[2*E]=a2; x1[3*E]=a3;
  } else {
    int bb = blk - 800;
    int b = bb/32; int l0 = (bb%32)*4;
    float (*st)[D_TXT] = (float(*)[D_TXT])sbuf;
    for (int i = tid; i < 4*D_TXT; i += 256){
      int li = i / D_TXT, k = i % D_TXT;
      st[li][k] = text[(b*L_TXT + l0 + li)*D_TXT + k];
    }
    __syncthreads();
    float bqe = bq[tid];
    float a0=bqe,a1=bqe,a2=bqe,a3=bqe;
    const float* wqt = ws + OFF_WQT;
    #pragma unroll 2
    for (int k=0;k<D_TXT;k++){
      float w = wqt[k*E + tid];
      a0 += st[0][k]*w; a1 += st[1][k]*w; a2 += st[2][k]*w; a3 += st[3][k]*w;
    }
    float* q1 = ws + OFF_Q1 + (b*L_TXT + l0)*E + tid;
    q1[0]=a0; q1[E]=a1; q1[2*E]=a2; q1[3*E]=a3;
  }
}

// ---- scores + masked softmax + context + h0 ; one block per (b,l)  [R18 shape] ----
__global__ __launch_bounds__(256) void k_score(const int* __restrict__ mel_len,
                                               float* __restrict__ ws,
                                               float* __restrict__ d_out){
  int blk = blockIdx.x; int b = blk >> 7; int l = blk & 127;
  int tid = threadIdx.x; int lane = tid & 63; int wv = tid >> 6;
  __shared__ __align__(16) float sl[T_MEL];
  __shared__ float red[8];
  const float* x1 = ws + OFF_X1 + b*T_MEL*E;
  const float* q1 = ws + OFF_Q1 + (b*L_TXT+l)*E;
  int g = lane >> 4, i = lane & 15;      // group (which t), e-chunk
  float qv[16], wvv[16];
  {
    const float4* q4 = (const float4*)(q1 + i*16);
    const float4* w4 = (const float4*)(ws + OFF_W + i*16);
    #pragma unroll
    for (int j=0;j<4;j++){
      float4 a = q4[j]; qv[4*j]=a.x; qv[4*j+1]=a.y; qv[4*j+2]=a.z; qv[4*j+3]=a.w;
      float4 c = w4[j]; wvv[4*j]=c.x; wvv[4*j+1]=c.y; wvv[4*j+2]=c.z; wvv[4*j+3]=c.w;
    }
  }
  float cc = ws[OFF_C];
  int len = mel_len[b];
  #pragma unroll 2
  for (int iter=0; iter<25; iter++){
    int t = iter*16 + wv*4 + g;
    const float4* xr = (const float4*)(x1 + t*E + i*16);
    float s = 0.f;
    #pragma unroll
    for (int j=0;j<4;j++){
      float4 xv = xr[j];
      s += wvv[4*j+0]*fast_tanh(xv.x + qv[4*j+0]);
      s += wvv[4*j+1]*fast_tanh(xv.y + qv[4*j+1]);
      s += wvv[4*j+2]*fast_tanh(xv.z + qv[4*j+2]);
      s += wvv[4*j+3]*fast_tanh(xv.w + qv[4*j+3]);
    }
    s += __shfl_xor(s,1); s += __shfl_xor(s,2);
    s += __shfl_xor(s,4); s += __shfl_xor(s,8);
    if (i==0) sl[t] = s + cc;
  }
  __syncthreads();
  float mx = -3.0e38f;
  for (int t = tid; t < T_MEL; t += 256) if (t < len) mx = fmaxf(mx, sl[t]);
  #pragma unroll
  for (int off=32; off>=1; off>>=1) mx = fmaxf(mx, __shfl_xor(mx, off));
  if (lane==0) red[wv] = mx;
  __syncthreads();
  mx = fmaxf(fmaxf(red[0],red[1]),fmaxf(red[2],red[3]));
  float se = 0.f;
  for (int t = tid; t < T_MEL; t += 256){
    float p = (t < len) ? __expf(sl[t]-mx) : 0.f;
    sl[t] = p; se += p;
  }
  #pragma unroll
  for (int off=32; off>=1; off>>=1) se += __shfl_xor(se, off);
  if (lane==0) red[4+wv] = se;
  __syncthreads();
  float rsum = 1.f/(red[4]+red[5]+red[6]+red[7]);
  float* sc_out = d_out + 1824 + (b*L_TXT + l)*T_MEL;
  for (int t = tid; t < T_MEL; t += 256){
    float p = sl[t]*rsum;
    sl[t] = p; sc_out[t] = p;
  }
  __syncthreads();
  float a = 0.f;
  int e = tid;
  for (int t = 0; t < T_MEL; t += 4){
    float4 p4 = *(const float4*)&sl[t];     // sl=0 past len -> no guard needed
    a += p4.x*x1[(t  )*E+e] + p4.y*x1[(t+1)*E+e]
       + p4.z*x1[(t+2)*E+e] + p4.w*x1[(t+3)*E+e];
  }
  ws[OFF_H0 + (b*L_TXT+l)*E + e] = q1[e] + a;
}

// ---- gates v5: output G[dir][t][b][u*4+gate], COALESCED via 16KB LDS transpose ----
__global__ __launch_bounds__(512) void k_gates(const float* __restrict__ in,
                                               const float* __restrict__ hs,
                                               const int* __restrict__ txt_len,
                                               float* __restrict__ gates, int layer,
                                               float* __restrict__ ws){
  int idx = blockIdx.x; int tt = idx & 15; int dir = (idx>>4)&1; int b = idx>>5;
  int tid = threadIdx.x;
  __shared__ __align__(16) uint sih[8][128];   // 8 rows x 128 f16-pairs (k = 2*k2)
  __shared__ float outb[8][512];               // transpose buffer for coalesced writes
  int len = txt_len[b];
  for (int i = tid; i < 8*128; i += 512){
    int r = i >> 7, k2 = i & 127;
    int t = tt*8 + r;
    int row = dir ? max(0, len-1-t) : t;
    float va, vb;
    if (layer == 0){
      const float2 p = *(const float2*)&in[((size_t)(b*L_TXT + row))*HID + 2*k2];
      va = p.x; vb = p.y;
    } else {
      int k = 2*k2; int d = k >> 7, u = k & 127;   // k even -> k,k+1 share d
      int sidx = (d==0) ? row : (row < len ? len-1-row : 0);
      const float2 p = *(const float2*)&hs[(((size_t)d*L_TXT + sidx)*8 + b)*128 + u];
      va = p.x; vb = p.y;
    }
    sih[r][k2] = packh2(va, vb);
  }
  __syncthreads();
  int ld = layer*2 + dir;
  int g = tid;
  float bsum = ws[OFF_BSUM + ld*512 + g];
  float acc[8];
  #pragma unroll
  for (int r=0;r<8;r++) acc[r] = bsum;
  const uint* wt2 = (const uint*)(ws + OFF_WIHT) + (size_t)ld*128*512 + g;
  for (int k4=0; k4<128; k4+=4){
    uint w0 = wt2[(k4  )*512];
    uint w1 = wt2[(k4+1)*512];
    uint w2 = wt2[(k4+2)*512];
    uint w3 = wt2[(k4+3)*512];
    #pragma unroll
    for (int r=0;r<8;r++){
      uint4 s4 = *(const uint4*)&sih[r][k4];
      acc[r] = fdot2(s4.x, w0, acc[r]);
      acc[r] = fdot2(s4.y, w1, acc[r]);
      acc[r] = fdot2(s4.z, w2, acc[r]);
      acc[r] = fdot2(s4.w, w3, acc[r]);
    }
  }
  #pragma unroll
  for (int r=0;r<8;r++) outb[r][g] = acc[r];
  __syncthreads();
  // permuted read (4-way bank alias, ~free) -> contiguous global write
  float* go = gates + (((size_t)(dir*L_TXT + tt*8)*8) + b)*512;
  int src = (tid & 3)*128 + (tid >> 2);      // gate row feeding output slot tid
  #pragma unroll
  for (int r=0;r<8;r++) go[(size_t)r*8*512 + tid] = outb[r][src];
}

// ---- recurrent scan v20: 512 thr; thread (u=tid>>2, pr=(tid>>1)&1, hf=tid&1)
// owns rows {pr*128+u, 256+pr*128+u} x half-h = 16 uint4 = 64 weight VGPRs
// (trivially resident: ~95 total << 256 budget at 2 waves/SIMD). shfl_xor(1)
// joins h-halves, shfl_xor(2) swaps activated (i,g)<->(f,o), shfl_xor(4) pairs
// h. LDS pad via h-double-buffer inside the 88KB read-every-step array. ----
__global__ __launch_bounds__(512) void k_scan(const float* __restrict__ Gp,
                                              const uint* __restrict__ wg,
                                              const int* __restrict__ txt_len,
                                              float* __restrict__ hseq,
                                              float* __restrict__ pooled, int layer){
  __shared__ uint wlds[22528];       // 88KB; [0..127] = h double-buffer (read every step)
  int dir = blockIdx.x & 1; int b = blockIdx.x >> 1;
  int tid = threadIdx.x;
  int l = tid & 63, w = tid >> 6;    // 8 waves
  int u  = tid >> 2;                 // unit 0..127
  int pr = (tid >> 1) & 1;           // 0: rows (i,g) ; 1: rows (f,o)
  int hf = tid & 1;                  // half of h

  // load both banks: 16 uint4 = 64 VGPR, pinned
  const uint* wgp = wg + (((size_t)(layer*2+dir))*8 + w)*4096 + l*4;
  uint4 wA[8], wB[8];
  #pragma unroll
  for (int jj=0;jj<8;jj++){
    wA[jj] = *(const uint4*)(wgp + (jj   )*256);
    wB[jj] = *(const uint4*)(wgp + (8+jj)*256);
  }
  #pragma unroll
  for (int jj=0;jj<8;jj++){
    asm volatile("" : "+v"(wA[jj].x), "+v"(wA[jj].y), "+v"(wA[jj].z), "+v"(wA[jj].w));
    asm volatile("" : "+v"(wB[jj].x), "+v"(wB[jj].y), "+v"(wB[jj].z), "+v"(wB[jj].w));
  }

  if (tid < 128) wlds[tid] = 0;      // zero both h buffers
  int len = txt_len[b];
  bool pool = (layer == 1);

  const float* gb = Gp + ((size_t)(dir*L_TXT)*8 + b)*512 + u*4;
  float gA = gb[pr], gB = gb[pr+2];  // (i,g) or (f,o) inputs for unit u
  float c_reg = 0.f, psum = 0.f;
  __syncthreads();

  for (int s=0; s<L_TXT; s++){
    const float* gn = gb + (size_t)(s+1 < L_TXT ? s+1 : s)*4096;
    float nA = gn[pr], nB = gn[pr+2];
    const uint4* hp = (const uint4*)(wlds + (s&1)*64 + hf*32);  // broadcast: 2 addrs/wave
    float aA = hf ? 0.f : gA;
    float aB = hf ? 0.f : gB;
    #pragma unroll
    for (int jj=0;jj<8;jj++){
      uint4 hv = hp[jj];
      uint4 a = wA[jj];
      uint4 c = wB[jj];
      aA = fdot2(a.x,hv.x,aA); aA = fdot2(a.y,hv.y,aA);
      aA = fdot2(a.z,hv.z,aA); aA = fdot2(a.w,hv.w,aA);
      aB = fdot2(c.x,hv.x,aB); aB = fdot2(c.y,hv.y,aB);
      aB = fdot2(c.z,hv.z,aB); aB = fdot2(c.w,hv.w,aB);
    }
    aA += __shfl_xor(aA, 1);   // join h-halves (tid^1 = same u,pr, other hf)
    aB += __shfl_xor(aB, 1);
    // activate own gates: A-row is i or f (sigmoid); B-row is g (tanh) or o (sigmoid)
    float vA = fast_sigmoid(aA);
    float vB = pr ? fast_sigmoid(aB) : fast_tanh(aB);
    float xA = __shfl_xor(vA, 2);  // partner's i/f
    float xB = __shfl_xor(vB, 2);  // partner's g/o
    float iv = pr ? xA : vA;
    float fv = pr ? vA : xA;
    float gv = pr ? xB : vB;
    float ov = pr ? vB : xB;
    c_reg = fv*c_reg + iv*gv;
    float h = ov*fast_tanh(c_reg);
    float hn = __shfl_xor(h, 4);           // unit u^1's h (same pr,hf)
    if (hf==0 && pr==0 && !(u&1)) wlds[((s+1)&1)*64 + (u>>1)] = packh2(h, hn);
    if (pool){
      if (s < len) psum += h;
    } else {
      if (hf==0 && pr==0) hseq[(((size_t)dir*L_TXT + s)*8 + b)*128 + u] = h;
    }
    gA = nA; gB = nB;
    __syncthreads();
  }
  if (pool && hf==0 && pr==0) pooled[((size_t)(dir*8+b))*128 + u] = psum;
}

// ---- p1/tanh + normalize + p2 ; pooling read from pooled[] (scan L1 fused it) ----
__global__ __launch_bounds__(256) void k_final(const float* __restrict__ pooled,
                                               const int* __restrict__ txt_len,
                                               const float* __restrict__ p1w,
                                               const float* __restrict__ p1b,
                                               const float* __restrict__ p2w,
                                               const float* __restrict__ p2b,
                                               float* __restrict__ d_out){
  int b = blockIdx.x; int tid = threadIdx.x;
  __shared__ float pl[HID];
  __shared__ float ol[EMB];
  __shared__ float nrm;
  int len = txt_len[b];
  int d = tid >> 7, u = tid & 127;
  pl[tid] = pooled[((size_t)(d*8+b))*128 + u] / (float)len;
  __syncthreads();
  if (tid < EMB){
    float a = p1b[tid];
    for (int k=0;k<HID;k++) a += pl[k]*p1w[tid*HID+k];
    ol[tid] = fast_tanh(a);
  }
  __syncthreads();
  if (tid == 0){
    float q = 0.f;
    for (int k=0;k<EMB;k++) q += ol[k]*ol[k];
    nrm = rsqrtf(q);
  }
  __syncthreads();
  if (tid < EMB) d_out[800 + b*EMB + tid] = ol[tid]*nrm;
  if (tid < N_SPK){
    float a = p2b[tid];
    for (int k=0;k<EMB;k++) a += ol[k]*p2w[tid*EMB+k];
    d_out[b*N_SPK + tid] = a;
  }
}

extern "C" void kernel_launch(void* const* d_in, const int* in_sizes, int n_in,
                              void* d_out, int out_size, void* d_ws, size_t ws_size,
                              hipStream_t stream) {
  const float* x       = (const float*)d_in[0];
  const int*   mel_len = (const int*)  d_in[1];
  const float* text    = (const float*)d_in[2];
  const int*   txt_len = (const int*)  d_in[3];
  const float* Wx      = (const float*)d_in[4];
  const float* bx      = (const float*)d_in[5];
  const float* Wq      = (const float*)d_in[6];
  const float* bq      = (const float*)d_in[7];
  const float* Wout    = (const float*)d_in[8];
  const float* bout    = (const float*)d_in[9];
  const float* v       = (const float*)d_in[10];
  const float* wih     = (const float*)d_in[11];
  const float* whh     = (const float*)d_in[12];
  const float* bih     = (const float*)d_in[13];
  const float* bhh     = (const float*)d_in[14];
  const float* p1w     = (const float*)d_in[15];
  const float* p1b     = (const float*)d_in[16];
  const float* p2w     = (const float*)d_in[17];
  const float* p2b     = (const float*)d_in[18];
  float* ws  = (float*)d_ws;
  float* out = (float*)d_out;
  const uint* wg = (const uint*)(ws + OFF_WG);

  k_prep <<<102, 256, 0, stream>>>(Wout, bout, v, Wx, Wq, wih, bih, bhh, whh, ws);
  k_xq   <<<1056, 256, 0, stream>>>(x, bx, text, bq, ws);
  k_score<<<1024, 256, 0, stream>>>(mel_len, ws, out);

  float* G = ws + OFF_G;
  k_gates<<<256, 512, 0, stream>>>(ws + OFF_H0, ws + OFF_HS0, txt_len, G, 0, ws);
  k_scan <<<16, 512, 0, stream>>>(G, wg, txt_len, ws + OFF_HS0, ws + OFF_POOL, 0);
  k_gates<<<256, 512, 0, stream>>>(ws + OFF_H0, ws + OFF_HS0, txt_len, G, 1, ws);
  k_scan <<<16, 512, 0, stream>>>(G, wg, txt_len, ws + OFF_HS0, ws + OFF_POOL, 1);

  k_final<<<8, 256, 0, stream>>>(ws + OFF_POOL, txt_len, p1w, p1b, p2w, p2b, out);
}

// Round 24
// 384.035 us; speedup vs baseline: 1.0529x; 1.0529x over previous
//
#include <hip/hip_runtime.h>
#include <hip/hip_bf16.h>
#include <math.h>

#define B 8
#define T_MEL 400
#define N_MEL 80
#define L_TXT 128
#define D_TXT 512
#define E 256
#define HID 256
#define EMB 128
#define N_SPK 100
#define HH 128

// ---- workspace layout (float element offsets) ----
#define OFF_W      0
#define OFF_C      256
#define OFF_WXT    272
#define OFF_WQT    (OFF_WXT + N_MEL*E)        // 20752
#define OFF_WIHT   (OFF_WQT + D_TXT*E)        // 151824 ; uint[4][128][512] f16-pairs (view-cast)
#define OFF_BSUM   (OFF_WIHT + 2*2*256*512)   // 676112
#define OFF_X1     (OFF_BSUM + 2048)          // 678160
#define OFF_Q1     (OFF_X1 + B*T_MEL*E)       // 1497360
#define OFF_G      OFF_X1                      // gates overlay x1 (dead by then)
#define OFF_H0     (OFF_Q1 + B*L_TXT*E)       // 1759504
#define OFF_O1     (OFF_H0 + B*L_TXT*E)       // 2021648
#define OFF_HS0    OFF_H0                      // hseq[2][128][8][128] overlays H0
#define OFF_POOL   OFF_O1                      // pooled[2][8][128] floats (written by scan L1)
#define OFF_WG     (OFF_O1 + 4096)            // uint[4][4][8192] Whh f16-pairs, wave-contig

typedef _Float16 half2v __attribute__((ext_vector_type(2)));

__device__ __forceinline__ float fast_sigmoid(float x){ return 1.f/(1.f+__expf(-x)); }
__device__ __forceinline__ float fast_tanh(float x){ float e=__expf(2.f*x); return 1.f - 2.f/(e+1.f); }

__device__ __forceinline__ float fdot2(uint a, uint b, float c){
  half2v ha = __builtin_bit_cast(half2v, a);
  half2v hb = __builtin_bit_cast(half2v, b);
#if __has_builtin(__builtin_amdgcn_fdot2)
  return __builtin_amdgcn_fdot2(ha, hb, c, false);
#else
  float r;
  asm("v_dot2_f32_f16 %0, %1, %2, %3" : "=v"(r) : "v"(a), "v"(b), "v"(c));
  return r;
#endif
}
__device__ __forceinline__ uint packh2(float a, float b){
  union { _Float16 h[2]; uint u; } x;
  x.h[0] = (_Float16)a; x.h[1] = (_Float16)b; return x.u;
}

// ---- prep v3: tiled LDS transposes (coalesced both sides) ----
// blocks: 0 w/c | 1..4 WXT | 5..36 WQT | 37..68 WIHT | 69 BSUM | 70..85 WG
__global__ __launch_bounds__(256) void k_prep(const float* __restrict__ Wout, const float* __restrict__ bout,
                       const float* __restrict__ v,    const float* __restrict__ Wx,
                       const float* __restrict__ Wq,   const float* __restrict__ wih,
                       const float* __restrict__ bih,  const float* __restrict__ bhh,
                       const float* __restrict__ whh,  float* __restrict__ ws){
  __shared__ __align__(16) float tile[64][81];
  __shared__ __align__(16) uint  utile[64][129];
  int blk = blockIdx.x, tid = threadIdx.x;
  if (blk == 0){
    float acc = 0.f;
    for (int j=0;j<E;j++) acc += Wout[j*E + tid] * v[j];
    ws[OFF_W + tid] = acc;
    if (tid==0){ float c=0.f; for(int j=0;j<E;j++) c += bout[j]*v[j]; ws[OFF_C]=c; }
  } else if (blk <= 4){
    int e0 = (blk-1)*64;
    for (int idx = tid; idx < 64*20; idx += 256){
      int e = idx/20, c4 = idx%20;
      float4 vv = *(const float4*)&Wx[(size_t)(e0+e)*N_MEL + 4*c4];
      tile[e][4*c4]=vv.x; tile[e][4*c4+1]=vv.y; tile[e][4*c4+2]=vv.z; tile[e][4*c4+3]=vv.w;
    }
    __syncthreads();
    for (int idx = tid; idx < N_MEL*64; idx += 256){
      int m = idx>>6, e = idx&63;
      ws[OFF_WXT + m*E + e0 + e] = tile[e][m];
    }
  } else if (blk <= 36){
    int t = blk-5; int e0 = (t&3)*64, k0 = (t>>2)*64;
    for (int idx = tid; idx < 64*16; idx += 256){
      int e = idx>>4, c = idx&15;
      float4 vv = *(const float4*)&Wq[(size_t)(e0+e)*D_TXT + k0 + 4*c];
      tile[e][4*c]=vv.x; tile[e][4*c+1]=vv.y; tile[e][4*c+2]=vv.z; tile[e][4*c+3]=vv.w;
    }
    __syncthreads();
    for (int idx = tid; idx < 64*64; idx += 256){
      int k = idx>>6, e = idx&63;
      ws[OFF_WQT + (k0+k)*E + e0 + e] = tile[e][k];
    }
  } else if (blk <= 68){
    int t = blk-37; int ld = t>>3, g0 = (t&7)*64;
    for (int idx = tid; idx < 64*64; idx += 256){
      int g = idx>>6, c = idx&63;
      float4 vv = *(const float4*)&wih[((size_t)(ld*512+g0+g))*256 + 4*c];
      utile[g][2*c]   = packh2(vv.x, vv.y);
      utile[g][2*c+1] = packh2(vv.z, vv.w);
    }
    __syncthreads();
    uint* wout = (uint*)(ws + OFF_WIHT) + (size_t)ld*128*512;
    for (int idx = tid; idx < 128*64; idx += 256){
      int k2 = idx>>6, g = idx&63;
      wout[(size_t)k2*512 + g0 + g] = utile[g][k2];
    }
  } else if (blk == 69){
    for (int i = tid; i < 2048; i += 256)
      ws[OFF_BSUM + i] = bih[i] + bhh[i];
  } else {
    int bp = blk - 70;              // 0..15
    int ld = bp >> 2, w = bp & 3;
    uint* wg = (uint*)(ws + OFF_WG) + ((size_t)ld*4 + w)*8192;
    for (int ii = 0; ii < 32; ii++){
      int i = ii*256 + tid;         // 0..8191
      int r  = i >> 11;
      int jj = (i >> 8) & 7;
      int l  = (i >> 2) & 63;
      int k  = i & 3;
      int u  = w*32 + (l >> 1);
      int hf = l & 1;
      const float* src = whh + ((size_t)(ld*512 + r*128 + u))*HH + 64*hf + jj*8 + 2*k;
      wg[i] = packh2(src[0], src[1]);
    }
  }
}

// ---- x1 (blk<800) | q1 (blk 800..1055) ; reads WXT/WQT written by k_prep ----
__global__ __launch_bounds__(256) void k_xq(const float* __restrict__ x,    const float* __restrict__ bx,
                                            const float* __restrict__ text, const float* __restrict__ bq,
                                            float* __restrict__ ws){
  __shared__ float sbuf[2048];
  int blk = blockIdx.x, tid = threadIdx.x;
  if (blk < 800){
    int b = blk/100; int t0 = (blk%100)*4;
    float (*sx)[4] = (float(*)[4])sbuf;
    for (int i = tid; i < N_MEL*4; i += 256){
      int m = i>>2, ii = i&3;
      sx[m][ii] = x[(b*N_MEL+m)*T_MEL + t0 + ii];
    }
    __syncthreads();
    float bxe = bx[tid];
    float a0=bxe,a1=bxe,a2=bxe,a3=bxe;
    const float* wxt = ws + OFF_WXT;
    #pragma unroll 4
    for (int m=0;m<N_MEL;m++){
      float w = wxt[m*E + tid];
      a0 += sx[m][0]*w; a1 += sx[m][1]*w; a2 += sx[m][2]*w; a3 += sx[m][3]*w;
    }
    float* x1 = ws + OFF_X1 + (b*T_MEL + t0)*E + tid;
    x1[0]=a0; x1[E]=a1; x1[2*E]=a2; x1[3*E]=a3;
  } else {
    int bb = blk - 800;
    int b = bb/32; int l0 = (bb%32)*4;
    float (*st)[D_TXT] = (float(*)[D_TXT])sbuf;
    for (int i = tid; i < 4*D_TXT; i += 256){
      int li = i / D_TXT, k = i % D_TXT;
      st[li][k] = text[(b*L_TXT + l0 + li)*D_TXT + k];
    }
    __syncthreads();
    float bqe = bq[tid];
    float a0=bqe,a1=bqe,a2=bqe,a3=bqe;
    const float* wqt = ws + OFF_WQT;
    #pragma unroll 2
    for (int k=0;k<D_TXT;k++){
      float w = wqt[k*E + tid];
      a0 += st[0][k]*w; a1 += st[1][k]*w; a2 += st[2][k]*w; a3 += st[3][k]*w;
    }
    float* q1 = ws + OFF_Q1 + (b*L_TXT + l0)*E + tid;
    q1[0]=a0; q1[E]=a1; q1[2*E]=a2; q1[3*E]=a3;
  }
}

// ---- scores + masked softmax + context + h0 ; one block per (b,l)  [R18 shape] ----
__global__ __launch_bounds__(256) void k_score(const int* __restrict__ mel_len,
                                               float* __restrict__ ws,
                                               float* __restrict__ d_out){
  int blk = blockIdx.x; int b = blk >> 7; int l = blk & 127;
  int tid = threadIdx.x; int lane = tid & 63; int wv = tid >> 6;
  __shared__ __align__(16) float sl[T_MEL];
  __shared__ float red[8];
  const float* x1 = ws + OFF_X1 + b*T_MEL*E;
  const float* q1 = ws + OFF_Q1 + (b*L_TXT+l)*E;
  int g = lane >> 4, i = lane & 15;      // group (which t), e-chunk
  float qv[16], wvv[16];
  {
    const float4* q4 = (const float4*)(q1 + i*16);
    const float4* w4 = (const float4*)(ws + OFF_W + i*16);
    #pragma unroll
    for (int j=0;j<4;j++){
      float4 a = q4[j]; qv[4*j]=a.x; qv[4*j+1]=a.y; qv[4*j+2]=a.z; qv[4*j+3]=a.w;
      float4 c = w4[j]; wvv[4*j]=c.x; wvv[4*j+1]=c.y; wvv[4*j+2]=c.z; wvv[4*j+3]=c.w;
    }
  }
  float cc = ws[OFF_C];
  int len = mel_len[b];
  #pragma unroll 2
  for (int iter=0; iter<25; iter++){
    int t = iter*16 + wv*4 + g;
    const float4* xr = (const float4*)(x1 + t*E + i*16);
    float s = 0.f;
    #pragma unroll
    for (int j=0;j<4;j++){
      float4 xv = xr[j];
      s += wvv[4*j+0]*fast_tanh(xv.x + qv[4*j+0]);
      s += wvv[4*j+1]*fast_tanh(xv.y + qv[4*j+1]);
      s += wvv[4*j+2]*fast_tanh(xv.z + qv[4*j+2]);
      s += wvv[4*j+3]*fast_tanh(xv.w + qv[4*j+3]);
    }
    s += __shfl_xor(s,1); s += __shfl_xor(s,2);
    s += __shfl_xor(s,4); s += __shfl_xor(s,8);
    if (i==0) sl[t] = s + cc;
  }
  __syncthreads();
  float mx = -3.0e38f;
  for (int t = tid; t < T_MEL; t += 256) if (t < len) mx = fmaxf(mx, sl[t]);
  #pragma unroll
  for (int off=32; off>=1; off>>=1) mx = fmaxf(mx, __shfl_xor(mx, off));
  if (lane==0) red[wv] = mx;
  __syncthreads();
  mx = fmaxf(fmaxf(red[0],red[1]),fmaxf(red[2],red[3]));
  float se = 0.f;
  for (int t = tid; t < T_MEL; t += 256){
    float p = (t < len) ? __expf(sl[t]-mx) : 0.f;
    sl[t] = p; se += p;
  }
  #pragma unroll
  for (int off=32; off>=1; off>>=1) se += __shfl_xor(se, off);
  if (lane==0) red[4+wv] = se;
  __syncthreads();
  float rsum = 1.f/(red[4]+red[5]+red[6]+red[7]);
  float* sc_out = d_out + 1824 + (b*L_TXT + l)*T_MEL;
  for (int t = tid; t < T_MEL; t += 256){
    float p = sl[t]*rsum;
    sl[t] = p; sc_out[t] = p;
  }
  __syncthreads();
  float a = 0.f;
  int e = tid;
  for (int t = 0; t < T_MEL; t += 4){
    float4 p4 = *(const float4*)&sl[t];     // sl=0 past len -> no guard needed
    a += p4.x*x1[(t  )*E+e] + p4.y*x1[(t+1)*E+e]
       + p4.z*x1[(t+2)*E+e] + p4.w*x1[(t+3)*E+e];
  }
  ws[OFF_H0 + (b*L_TXT+l)*E + e] = q1[e] + a;
}

// ---- gates v5: output G[dir][t][b][u*4+gate], COALESCED via 16KB LDS transpose ----
__global__ __launch_bounds__(512) void k_gates(const float* __restrict__ in,
                                               const float* __restrict__ hs,
                                               const int* __restrict__ txt_len,
                                               float* __restrict__ gates, int layer,
                                               float* __restrict__ ws){
  int idx = blockIdx.x; int tt = idx & 15; int dir = (idx>>4)&1; int b = idx>>5;
  int tid = threadIdx.x;
  __shared__ __align__(16) uint sih[8][128];   // 8 rows x 128 f16-pairs (k = 2*k2)
  __shared__ float outb[8][512];               // transpose buffer for coalesced writes
  int len = txt_len[b];
  for (int i = tid; i < 8*128; i += 512){
    int r = i >> 7, k2 = i & 127;
    int t = tt*8 + r;
    int row = dir ? max(0, len-1-t) : t;
    float va, vb;
    if (layer == 0){
      const float2 p = *(const float2*)&in[((size_t)(b*L_TXT + row))*HID + 2*k2];
      va = p.x; vb = p.y;
    } else {
      int k = 2*k2; int d = k >> 7, u = k & 127;   // k even -> k,k+1 share d
      int sidx = (d==0) ? row : (row < len ? len-1-row : 0);
      const float2 p = *(const float2*)&hs[(((size_t)d*L_TXT + sidx)*8 + b)*128 + u];
      va = p.x; vb = p.y;
    }
    sih[r][k2] = packh2(va, vb);
  }
  __syncthreads();
  int ld = layer*2 + dir;
  int g = tid;
  float bsum = ws[OFF_BSUM + ld*512 + g];
  float acc[8];
  #pragma unroll
  for (int r=0;r<8;r++) acc[r] = bsum;
  const uint* wt2 = (const uint*)(ws + OFF_WIHT) + (size_t)ld*128*512 + g;
  for (int k4=0; k4<128; k4+=4){
    uint w0 = wt2[(k4  )*512];
    uint w1 = wt2[(k4+1)*512];
    uint w2 = wt2[(k4+2)*512];
    uint w3 = wt2[(k4+3)*512];
    #pragma unroll
    for (int r=0;r<8;r++){
      uint4 s4 = *(const uint4*)&sih[r][k4];
      acc[r] = fdot2(s4.x, w0, acc[r]);
      acc[r] = fdot2(s4.y, w1, acc[r]);
      acc[r] = fdot2(s4.z, w2, acc[r]);
      acc[r] = fdot2(s4.w, w3, acc[r]);
    }
  }
  #pragma unroll
  for (int r=0;r<8;r++) outb[r][g] = acc[r];
  __syncthreads();
  // permuted read (4-way bank alias, ~free) -> contiguous global write
  float* go = gates + (((size_t)(dir*L_TXT + tt*8)*8) + b)*512;
  int src = (tid & 3)*128 + (tid >> 2);      // gate row feeding output slot tid
  #pragma unroll
  for (int r=0;r<8;r++) go[(size_t)r*8*512 + tid] = outb[r][src];
}

// ---- recurrent scan v19 (R22, best measured: 93us, VGPR 132, LDS 90112).
// ALL FOUR gate banks in registers (128 VGPR, pinned); occupancy pad that
// cannot be eliminated: the h double-buffer lives in the first 128 uints of
// an 88KB __shared__ array the loop reads EVERY step. 1 block/CU. ----
__global__ __launch_bounds__(256) void k_scan(const float* __restrict__ Gp,
                                              const uint* __restrict__ wg,
                                              const int* __restrict__ txt_len,
                                              float* __restrict__ hseq,
                                              float* __restrict__ pooled, int layer){
  __shared__ uint wlds[22528];       // 88KB; [0..127] = h double-buffer (genuinely read)
  int dir = blockIdx.x & 1; int b = blockIdx.x >> 1;
  int tid = threadIdx.x;
  int l = tid & 63, w = tid >> 6;    // 4 waves
  int u  = tid >> 1;                 // unit 0..127
  int hf = tid & 1;                  // half of h

  // load all 4 gate banks: rows {u,128+u,256+u,384+u}, cols [64hf,64hf+64) as f16 pairs
  const uint* wgp = wg + (((size_t)(layer*2+dir))*4 + w)*8192 + l*4;
  uint4 wi[8], wf[8], wgg[8], wo[8];
  #pragma unroll
  for (int jj=0;jj<8;jj++){
    wi [jj] = *(const uint4*)(wgp + (jj   )*256);
    wf [jj] = *(const uint4*)(wgp + ( 8+jj)*256);
    wgg[jj] = *(const uint4*)(wgp + (16+jj)*256);
    wo [jj] = *(const uint4*)(wgp + (24+jj)*256);
  }
  // pin all four banks in VGPRs
  #pragma unroll
  for (int jj=0;jj<8;jj++){
    asm volatile("" : "+v"(wi [jj].x), "+v"(wi [jj].y), "+v"(wi [jj].z), "+v"(wi [jj].w));
    asm volatile("" : "+v"(wf [jj].x), "+v"(wf [jj].y), "+v"(wf [jj].z), "+v"(wf [jj].w));
    asm volatile("" : "+v"(wgg[jj].x), "+v"(wgg[jj].y), "+v"(wgg[jj].z), "+v"(wgg[jj].w));
    asm volatile("" : "+v"(wo [jj].x), "+v"(wo [jj].y), "+v"(wo [jj].z), "+v"(wo [jj].w));
  }

  if (tid < 128) wlds[tid] = 0;      // zero both h buffers
  int len = txt_len[b];
  bool pool = (layer == 1);

  const float* gb = Gp + ((size_t)(dir*L_TXT)*8 + b)*512 + u*4;
  float4 q = *(const float4*)gb;     // {i,f,g,o} gate inputs for unit u
  float c_reg = 0.f, psum = 0.f;
  __syncthreads();

  for (int s=0; s<L_TXT; s++){
    const float* gn = gb + (size_t)(s+1 < L_TXT ? s+1 : s)*4096;
    float4 qn = *(const float4*)gn;
    const uint4* hp = (const uint4*)(wlds + (s&1)*64 + hf*32);  // broadcast: 2 addrs/wave
    float a0 = hf ? 0.f : q.x;
    float a1 = hf ? 0.f : q.y;
    float a2 = hf ? 0.f : q.z;
    float a3 = hf ? 0.f : q.w;
    #pragma unroll
    for (int jj=0;jj<8;jj++){
      uint4 hv = hp[jj];
      uint4 w0 = wi [jj];
      uint4 w1 = wf [jj];
      uint4 w2 = wgg[jj];
      uint4 w3 = wo [jj];
      a0 = fdot2(w0.x,hv.x,a0); a0 = fdot2(w0.y,hv.y,a0);
      a0 = fdot2(w0.z,hv.z,a0); a0 = fdot2(w0.w,hv.w,a0);
      a1 = fdot2(w1.x,hv.x,a1); a1 = fdot2(w1.y,hv.y,a1);
      a1 = fdot2(w1.z,hv.z,a1); a1 = fdot2(w1.w,hv.w,a1);
      a2 = fdot2(w2.x,hv.x,a2); a2 = fdot2(w2.y,hv.y,a2);
      a2 = fdot2(w2.z,hv.z,a2); a2 = fdot2(w2.w,hv.w,a2);
      a3 = fdot2(w3.x,hv.x,a3); a3 = fdot2(w3.y,hv.y,a3);
      a3 = fdot2(w3.z,hv.z,a3); a3 = fdot2(w3.w,hv.w,a3);
    }
    a0 += __shfl_xor(a0, 1);   // join h-halves (tid^1 = same u, other hf)
    a1 += __shfl_xor(a1, 1);
    a2 += __shfl_xor(a2, 1);
    a3 += __shfl_xor(a3, 1);
    float i_ = fast_sigmoid(a0);
    float f_ = fast_sigmoid(a1);
    float g_ = fast_tanh   (a2);
    float o_ = fast_sigmoid(a3);
    c_reg = f_*c_reg + i_*g_;
    float h = o_*fast_tanh(c_reg);
    float hn = __shfl_xor(h, 2);           // unit u^1's h (same hf)
    if (hf==0 && !(u&1)) wlds[((s+1)&1)*64 + (u>>1)] = packh2(h, hn);
    if (pool){
      if (s < len) psum += h;
    } else {
      if (hf==0) hseq[(((size_t)dir*L_TXT + s)*8 + b)*128 + u] = h;  // coalesced
    }
    q = qn;
    __syncthreads();
  }
  if (pool && hf==0) pooled[((size_t)(dir*8+b))*128 + u] = psum;
}

// ---- p1/tanh + normalize + p2 ; pooling read from pooled[] (scan L1 fused it) ----
__global__ __launch_bounds__(256) void k_final(const float* __restrict__ pooled,
                                               const int* __restrict__ txt_len,
                                               const float* __restrict__ p1w,
                                               const float* __restrict__ p1b,
                                               const float* __restrict__ p2w,
                                               const float* __restrict__ p2b,
                                               float* __restrict__ d_out){
  int b = blockIdx.x; int tid = threadIdx.x;
  __shared__ float pl[HID];
  __shared__ float ol[EMB];
  __shared__ float nrm;
  int len = txt_len[b];
  int d = tid >> 7, u = tid & 127;
  pl[tid] = pooled[((size_t)(d*8+b))*128 + u] / (float)len;
  __syncthreads();
  if (tid < EMB){
    float a = p1b[tid];
    for (int k=0;k<HID;k++) a += pl[k]*p1w[tid*HID+k];
    ol[tid] = fast_tanh(a);
  }
  __syncthreads();
  if (tid == 0){
    float q = 0.f;
    for (int k=0;k<EMB;k++) q += ol[k]*ol[k];
    nrm = rsqrtf(q);
  }
  __syncthreads();
  if (tid < EMB) d_out[800 + b*EMB + tid] = ol[tid]*nrm;
  if (tid < N_SPK){
    float a = p2b[tid];
    for (int k=0;k<EMB;k++) a += ol[k]*p2w[tid*EMB+k];
    d_out[b*N_SPK + tid] = a;
  }
}

extern "C" void kernel_launch(void* const* d_in, const int* in_sizes, int n_in,
                              void* d_out, int out_size, void* d_ws, size_t ws_size,
                              hipStream_t stream) {
  const float* x       = (const float*)d_in[0];
  const int*   mel_len = (const int*)  d_in[1];
  const float* text    = (const float*)d_in[2];
  const int*   txt_len = (const int*)  d_in[3];
  const float* Wx      = (const float*)d_in[4];
  const float* bx      = (const float*)d_in[5];
  const float* Wq      = (const float*)d_in[6];
  const float* bq      = (const float*)d_in[7];
  const float* Wout    = (const float*)d_in[8];
  const float* bout    = (const float*)d_in[9];
  const float* v       = (const float*)d_in[10];
  const float* wih     = (const float*)d_in[11];
  const float* whh     = (const float*)d_in[12];
  const float* bih     = (const float*)d_in[13];
  const float* bhh     = (const float*)d_in[14];
  const float* p1w     = (const float*)d_in[15];
  const float* p1b     = (const float*)d_in[16];
  const float* p2w     = (const float*)d_in[17];
  const float* p2b     = (const float*)d_in[18];
  float* ws  = (float*)d_ws;
  float* out = (float*)d_out;
  const uint* wg = (const uint*)(ws + OFF_WG);

  k_prep <<<86, 256, 0, stream>>>(Wout, bout, v, Wx, Wq, wih, bih, bhh, whh, ws);
  k_xq   <<<1056, 256, 0, stream>>>(x, bx, text, bq, ws);
  k_score<<<1024, 256, 0, stream>>>(mel_len, ws, out);

  float* G = ws + OFF_G;
  k_gates<<<256, 512, 0, stream>>>(ws + OFF_H0, ws + OFF_HS0, txt_len, G, 0, ws);
  k_scan <<<16, 256, 0, stream>>>(G, wg, txt_len, ws + OFF_HS0, ws + OFF_POOL, 0);
  k_gates<<<256, 512, 0, stream>>>(ws + OFF_H0, ws + OFF_HS0, txt_len, G, 1, ws);
  k_scan <<<16, 256, 0, stream>>>(G, wg, txt_len, ws + OFF_HS0, ws + OFF_POOL, 1);

  k_final<<<8, 256, 0, stream>>>(ws + OFF_POOL, txt_len, p1w, p1b, p2w, p2b, out);
}